// Round 1
// baseline (3568.031 us; speedup 1.0000x reference)
//
#include <hip/hip_runtime.h>
#include <math.h>

#define B_ 2
#define S_ 2048
#define E_ 1024
#define H_ 16
#define D_ 64
#define TOK (B_*S_)          // 4096 tokens
#define SCALE 45.254833995939045f   // sqrt(2048): reference's softmax(scores / S**-0.5)

// ---------------------------------------------------------------------------
// Kernel 1: per-head QKV projection. q[b,s,h,i] = sum_d x[b,s,h,d] * W[i,d]
// One block per token; stage the 3 input rows (1024 fl each) in LDS.
// ---------------------------------------------------------------------------
__global__ __launch_bounds__(256) void qkv_proj(
    const float* __restrict__ xq, const float* __restrict__ xk,
    const float* __restrict__ xv,
    const float* __restrict__ Wq, const float* __restrict__ Wk,
    const float* __restrict__ Wv,
    float* __restrict__ q, float* __restrict__ k, float* __restrict__ v) {
  __shared__ float lx0[E_], lx1[E_], lx2[E_];
  const int tok = blockIdx.x;
  const int t = threadIdx.x;
  const float4* xq4 = (const float4*)(xq + (size_t)tok * E_);
  const float4* xk4 = (const float4*)(xk + (size_t)tok * E_);
  const float4* xv4 = (const float4*)(xv + (size_t)tok * E_);
  ((float4*)lx0)[t] = xq4[t];
  ((float4*)lx1)[t] = xk4[t];
  ((float4*)lx2)[t] = xv4[t];
  __syncthreads();
  #pragma unroll
  for (int rep = 0; rep < 4; rep++) {
    const int e = t + rep * 256;       // 0..1023 output channel
    const int hh = e >> 6, rr = e & 63;
    const float4* wq4 = (const float4*)(Wq + rr * D_);
    const float4* wk4 = (const float4*)(Wk + rr * D_);
    const float4* wv4 = (const float4*)(Wv + rr * D_);
    const float4* lq4 = (const float4*)(&lx0[hh * D_]);
    const float4* lk4 = (const float4*)(&lx1[hh * D_]);
    const float4* lv4 = (const float4*)(&lx2[hh * D_]);
    float aq = 0.f, ak = 0.f, av = 0.f;
    #pragma unroll
    for (int d4 = 0; d4 < 16; d4++) {
      float4 w, x;
      w = wq4[d4]; x = lq4[d4];
      aq = fmaf(w.x, x.x, aq); aq = fmaf(w.y, x.y, aq);
      aq = fmaf(w.z, x.z, aq); aq = fmaf(w.w, x.w, aq);
      w = wk4[d4]; x = lk4[d4];
      ak = fmaf(w.x, x.x, ak); ak = fmaf(w.y, x.y, ak);
      ak = fmaf(w.z, x.z, ak); ak = fmaf(w.w, x.w, ak);
      w = wv4[d4]; x = lv4[d4];
      av = fmaf(w.x, x.x, av); av = fmaf(w.y, x.y, av);
      av = fmaf(w.z, x.z, av); av = fmaf(w.w, x.w, av);
    }
    q[(size_t)tok * E_ + e] = aq;
    k[(size_t)tok * E_ + e] = ak;
    v[(size_t)tok * E_ + e] = av;
  }
}

// ---------------------------------------------------------------------------
// Kernel 2: flash attention (fp32, online softmax).
// grid = (B*H, S/256); one thread owns one query row. K/V tiles of 64 rows
// staged in LDS; all lanes read in lockstep -> broadcast (conflict-free).
// attn = softmax(scores * sqrt(S))   [reference quirk: * sqrt(S), not /]
// ---------------------------------------------------------------------------
__global__ __launch_bounds__(256) void flash_attn(
    const float* __restrict__ q, const float* __restrict__ k,
    const float* __restrict__ v, float* __restrict__ ctx) {
  __shared__ float Ks[64][64];
  __shared__ float Vs[64][64];
  const int bh = blockIdx.x;                 // 0..31
  const int b = bh >> 4, h = bh & 15;
  const int srow = blockIdx.y * 256 + threadIdx.x;
  const int t = threadIdx.x;

  float qr[64];
  {
    const float4* qrow = (const float4*)(q + (((size_t)(b * S_ + srow)) * H_ + h) * D_);
    #pragma unroll
    for (int d4 = 0; d4 < 16; d4++) {
      float4 tmp = qrow[d4];
      qr[4 * d4 + 0] = tmp.x; qr[4 * d4 + 1] = tmp.y;
      qr[4 * d4 + 2] = tmp.z; qr[4 * d4 + 3] = tmp.w;
    }
  }
  float acc[64];
  #pragma unroll
  for (int d = 0; d < 64; d++) acc[d] = 0.f;
  float m = -1e30f, l = 0.f;

  for (int kt = 0; kt < S_ / 64; kt++) {
    __syncthreads();   // previous tile fully consumed before overwrite
    #pragma unroll
    for (int r = 0; r < 4; r++) {
      const int e4 = t + r * 256;            // 0..1023
      const int j = e4 >> 4, d4 = e4 & 15;
      const size_t base = (((size_t)(b * S_ + kt * 64 + j)) * H_ + h) * D_ + d4 * 4;
      *(float4*)&Ks[j][d4 * 4] = *(const float4*)(k + base);
      *(float4*)&Vs[j][d4 * 4] = *(const float4*)(v + base);
    }
    __syncthreads();

    for (int j = 0; j < 64; j++) {
      const float4* krow = (const float4*)Ks[j];
      float s0 = 0.f, s1 = 0.f, s2 = 0.f, s3 = 0.f;
      #pragma unroll
      for (int d4 = 0; d4 < 16; d4++) {
        float4 kk = krow[d4];
        s0 = fmaf(qr[4 * d4 + 0], kk.x, s0);
        s1 = fmaf(qr[4 * d4 + 1], kk.y, s1);
        s2 = fmaf(qr[4 * d4 + 2], kk.z, s2);
        s3 = fmaf(qr[4 * d4 + 3], kk.w, s3);
      }
      const float s = ((s0 + s1) + (s2 + s3)) * SCALE;
      const float4* vrow = (const float4*)Vs[j];
      if (s <= m) {
        const float p = __expf(s - m);
        l += p;
        #pragma unroll
        for (int d4 = 0; d4 < 16; d4++) {
          float4 vv = vrow[d4];
          acc[4 * d4 + 0] = fmaf(p, vv.x, acc[4 * d4 + 0]);
          acc[4 * d4 + 1] = fmaf(p, vv.y, acc[4 * d4 + 1]);
          acc[4 * d4 + 2] = fmaf(p, vv.z, acc[4 * d4 + 2]);
          acc[4 * d4 + 3] = fmaf(p, vv.w, acc[4 * d4 + 3]);
        }
      } else {
        const float alpha = __expf(m - s);   // exp(-1e30-s)==0 on first key
        m = s;
        l = fmaf(l, alpha, 1.0f);
        #pragma unroll
        for (int d4 = 0; d4 < 16; d4++) {
          float4 vv = vrow[d4];
          acc[4 * d4 + 0] = fmaf(acc[4 * d4 + 0], alpha, vv.x);
          acc[4 * d4 + 1] = fmaf(acc[4 * d4 + 1], alpha, vv.y);
          acc[4 * d4 + 2] = fmaf(acc[4 * d4 + 2], alpha, vv.z);
          acc[4 * d4 + 3] = fmaf(acc[4 * d4 + 3], alpha, vv.w);
        }
      }
    }
  }
  const float inv = 1.0f / l;
  float4* crow = (float4*)(ctx + (((size_t)(b * S_ + srow)) * H_ + h) * D_);
  #pragma unroll
  for (int d4 = 0; d4 < 16; d4++) {
    float4 o;
    o.x = acc[4 * d4 + 0] * inv; o.y = acc[4 * d4 + 1] * inv;
    o.z = acc[4 * d4 + 2] * inv; o.w = acc[4 * d4 + 3] * inv;
    crow[d4] = o;
  }
}

// ---------------------------------------------------------------------------
// Kernel 3: C[M,N] = A[M,K] @ W[N,K]^T + bias (+optional ReLU). fp32 tiled.
// 64x64 block tile, 256 threads, 4x4 microtile, BK=16, LDS transposed +4 pad
// (row length 68 fl = 272 B, a 16 B multiple -> float4 LDS reads stay aligned).
// ---------------------------------------------------------------------------
template <int RELU>
__global__ __launch_bounds__(256) void gemm_bt(
    const float* __restrict__ A, const float* __restrict__ W,
    const float* __restrict__ bias, float* __restrict__ C,
    int M, int N, int K) {
  __shared__ float As[16][68];
  __shared__ float Bs[16][68];
  const int t = threadIdx.x;
  const int m0 = blockIdx.y * 64, n0 = blockIdx.x * 64;
  const int tr = t >> 4, tc = t & 15;
  const int lrow = t >> 2;     // 0..63
  const int lk4 = t & 3;       // 0..3 (float4 along K)
  float acc[4][4];
  #pragma unroll
  for (int i = 0; i < 4; i++)
    #pragma unroll
    for (int j = 0; j < 4; j++) acc[i][j] = 0.f;

  const float* Ap = A + (size_t)(m0 + lrow) * K + lk4 * 4;
  const float* Wp = W + (size_t)(n0 + lrow) * K + lk4 * 4;

  for (int k0 = 0; k0 < K; k0 += 16) {
    __syncthreads();
    float4 av = *(const float4*)(Ap + k0);
    float4 bv = *(const float4*)(Wp + k0);
    As[lk4 * 4 + 0][lrow] = av.x; As[lk4 * 4 + 1][lrow] = av.y;
    As[lk4 * 4 + 2][lrow] = av.z; As[lk4 * 4 + 3][lrow] = av.w;
    Bs[lk4 * 4 + 0][lrow] = bv.x; Bs[lk4 * 4 + 1][lrow] = bv.y;
    Bs[lk4 * 4 + 2][lrow] = bv.z; Bs[lk4 * 4 + 3][lrow] = bv.w;
    __syncthreads();
    #pragma unroll
    for (int kk = 0; kk < 16; kk++) {
      float4 a4 = *(const float4*)&As[kk][tr * 4];
      float4 b4 = *(const float4*)&Bs[kk][tc * 4];
      float ar[4] = {a4.x, a4.y, a4.z, a4.w};
      float br[4] = {b4.x, b4.y, b4.z, b4.w};
      #pragma unroll
      for (int i = 0; i < 4; i++)
        #pragma unroll
        for (int j = 0; j < 4; j++)
          acc[i][j] = fmaf(ar[i], br[j], acc[i][j]);
    }
  }
  const float4 bb = *(const float4*)(bias + n0 + tc * 4);
  #pragma unroll
  for (int i = 0; i < 4; i++) {
    float4 o;
    o.x = acc[i][0] + bb.x; o.y = acc[i][1] + bb.y;
    o.z = acc[i][2] + bb.z; o.w = acc[i][3] + bb.w;
    if (RELU) {
      o.x = fmaxf(o.x, 0.f); o.y = fmaxf(o.y, 0.f);
      o.z = fmaxf(o.z, 0.f); o.w = fmaxf(o.w, 0.f);
    }
    *(float4*)(C + (size_t)(m0 + tr * 4 + i) * N + n0 + tc * 4) = o;
  }
}

// ---------------------------------------------------------------------------
// Kernel 4: out = LayerNorm(a + r) * g + b. One block per token (256 thr x
// 4 fl each), wave shuffle reduce + tiny LDS cross-wave combine.
// ---------------------------------------------------------------------------
__global__ __launch_bounds__(256) void add_ln(
    const float* __restrict__ a, const float* __restrict__ r,
    const float* __restrict__ g, const float* __restrict__ bt,
    float* __restrict__ out) {
  __shared__ float red[16];
  const int tok = blockIdx.x, t = threadIdx.x;
  float4 av = ((const float4*)(a + (size_t)tok * E_))[t];
  float4 rv = ((const float4*)(r + (size_t)tok * E_))[t];
  float4 x;
  x.x = av.x + rv.x; x.y = av.y + rv.y; x.z = av.z + rv.z; x.w = av.w + rv.w;
  float sum = x.x + x.y + x.z + x.w;
  float ssq = x.x * x.x + x.y * x.y + x.z * x.z + x.w * x.w;
  #pragma unroll
  for (int off = 32; off >= 1; off >>= 1) {
    sum += __shfl_down(sum, off, 64);
    ssq += __shfl_down(ssq, off, 64);
  }
  const int wave = t >> 6;
  if ((t & 63) == 0) { red[wave] = sum; red[4 + wave] = ssq; }
  __syncthreads();
  if (t == 0) {
    float s = red[0] + red[1] + red[2] + red[3];
    float qq = red[4] + red[5] + red[6] + red[7];
    float mu = s * (1.0f / E_);
    red[8] = mu;
    red[9] = qq * (1.0f / E_) - mu * mu;
  }
  __syncthreads();
  const float mu = red[8];
  const float inv = rsqrtf(red[9] + 1e-5f);
  float4 gv = ((const float4*)g)[t];
  float4 bv = ((const float4*)bt)[t];
  float4 o;
  o.x = (x.x - mu) * inv * gv.x + bv.x;
  o.y = (x.y - mu) * inv * gv.y + bv.y;
  o.z = (x.z - mu) * inv * gv.z + bv.z;
  o.w = (x.w - mu) * inv * gv.w + bv.w;
  ((float4*)(out + (size_t)tok * E_))[t] = o;
}

// ---------------------------------------------------------------------------
extern "C" void kernel_launch(void* const* d_in, const int* in_sizes, int n_in,
                              void* d_out, int out_size, void* d_ws, size_t ws_size,
                              hipStream_t stream) {
  const float* queries = (const float*)d_in[0];
  const float* keys    = (const float*)d_in[1];
  const float* values  = (const float*)d_in[2];
  // d_in[3] = mask: ignored (faithful to reference)
  const float* Wq  = (const float*)d_in[4];
  const float* Wk  = (const float*)d_in[5];
  const float* Wv  = (const float*)d_in[6];
  const float* Wfc = (const float*)d_in[7];
  const float* bfc = (const float*)d_in[8];
  const float* W1  = (const float*)d_in[9];
  const float* b1  = (const float*)d_in[10];
  const float* W2  = (const float*)d_in[11];
  const float* b2  = (const float*)d_in[12];
  const float* ln1_g = (const float*)d_in[13];
  const float* ln1_b = (const float*)d_in[14];
  const float* ln2_g = (const float*)d_in[15];
  const float* ln2_b = (const float*)d_in[16];

  float* ws = (float*)d_ws;
  // layout (floats): [Q 4M][K 4M][V 4M][CTX 4M][FF1 16M]  = 32M fl = 128 MB
  float* Q    = ws;
  float* Kp   = ws + 4194304;
  float* Vp   = ws + 8388608;
  float* CTX  = ws + 12582912;
  float* FF1  = ws + 16777216;
  float* ATT  = Q;     // Q dead after attention
  float* Hbuf = Kp;    // K dead after attention
  float* X    = Vp;    // V dead after attention
  float* out  = (float*)d_out;

  qkv_proj<<<TOK, 256, 0, stream>>>(queries, keys, values, Wq, Wk, Wv, Q, Kp, Vp);
  flash_attn<<<dim3(B_ * H_, S_ / 256), 256, 0, stream>>>(Q, Kp, Vp, CTX);
  gemm_bt<0><<<dim3(E_ / 64, TOK / 64), 256, 0, stream>>>(CTX, Wfc, bfc, ATT, TOK, E_, E_);
  add_ln<<<TOK, 256, 0, stream>>>(ATT, queries, ln1_g, ln1_b, Hbuf);
  gemm_bt<1><<<dim3(4 * E_ / 64, TOK / 64), 256, 0, stream>>>(Hbuf, W1, b1, FF1, TOK, 4 * E_, E_);
  gemm_bt<0><<<dim3(E_ / 64, TOK / 64), 256, 0, stream>>>(FF1, W2, b2, X, TOK, E_, 4 * E_);
  add_ln<<<TOK, 256, 0, stream>>>(X, Hbuf, ln2_g, ln2_b, out);
}

// Round 2
// 2555.532 us; speedup vs baseline: 1.3962x; 1.3962x over previous
//
#include <hip/hip_runtime.h>
#include <hip/hip_bf16.h>
#include <math.h>

#define B_ 2
#define S_ 2048
#define E_ 1024
#define H_ 16
#define D_ 64
#define TOK (B_*S_)          // 4096 tokens
#define SCALE 45.254833995939045f   // sqrt(2048): reference's softmax(scores / S**-0.5)

typedef __bf16 bf16x8 __attribute__((ext_vector_type(8)));
typedef float floatx4 __attribute__((ext_vector_type(4)));
struct b4s { __hip_bfloat16 x, y, z, w; };   // 8-byte packed bf16 quad

// ---------------------------------------------------------------------------
// fp32 -> bf16 cast (for weights), float4 in / 8B out per thread
// ---------------------------------------------------------------------------
__global__ __launch_bounds__(256) void cast_f2b(
    const float* __restrict__ in, __hip_bfloat16* __restrict__ out, int n4) {
  int i = blockIdx.x * 256 + threadIdx.x;
  if (i < n4) {
    float4 v = ((const float4*)in)[i];
    b4s o;
    o.x = __float2bfloat16(v.x); o.y = __float2bfloat16(v.y);
    o.z = __float2bfloat16(v.z); o.w = __float2bfloat16(v.w);
    *(b4s*)(out + (size_t)i * 4) = o;
  }
}

// ---------------------------------------------------------------------------
// Kernel 1: per-head QKV projection (fp32, unchanged from round 0)
// ---------------------------------------------------------------------------
__global__ __launch_bounds__(256) void qkv_proj(
    const float* __restrict__ xq, const float* __restrict__ xk,
    const float* __restrict__ xv,
    const float* __restrict__ Wq, const float* __restrict__ Wk,
    const float* __restrict__ Wv,
    float* __restrict__ q, float* __restrict__ k, float* __restrict__ v) {
  __shared__ float lx0[E_], lx1[E_], lx2[E_];
  const int tok = blockIdx.x;
  const int t = threadIdx.x;
  ((float4*)lx0)[t] = ((const float4*)(xq + (size_t)tok * E_))[t];
  ((float4*)lx1)[t] = ((const float4*)(xk + (size_t)tok * E_))[t];
  ((float4*)lx2)[t] = ((const float4*)(xv + (size_t)tok * E_))[t];
  __syncthreads();
  #pragma unroll
  for (int rep = 0; rep < 4; rep++) {
    const int e = t + rep * 256;
    const int hh = e >> 6, rr = e & 63;
    const float4* wq4 = (const float4*)(Wq + rr * D_);
    const float4* wk4 = (const float4*)(Wk + rr * D_);
    const float4* wv4 = (const float4*)(Wv + rr * D_);
    const float4* lq4 = (const float4*)(&lx0[hh * D_]);
    const float4* lk4 = (const float4*)(&lx1[hh * D_]);
    const float4* lv4 = (const float4*)(&lx2[hh * D_]);
    float aq = 0.f, ak = 0.f, av = 0.f;
    #pragma unroll
    for (int d4 = 0; d4 < 16; d4++) {
      float4 w, x;
      w = wq4[d4]; x = lq4[d4];
      aq = fmaf(w.x, x.x, aq); aq = fmaf(w.y, x.y, aq);
      aq = fmaf(w.z, x.z, aq); aq = fmaf(w.w, x.w, aq);
      w = wk4[d4]; x = lk4[d4];
      ak = fmaf(w.x, x.x, ak); ak = fmaf(w.y, x.y, ak);
      ak = fmaf(w.z, x.z, ak); ak = fmaf(w.w, x.w, ak);
      w = wv4[d4]; x = lv4[d4];
      av = fmaf(w.x, x.x, av); av = fmaf(w.y, x.y, av);
      av = fmaf(w.z, x.z, av); av = fmaf(w.w, x.w, av);
    }
    q[(size_t)tok * E_ + e] = aq;
    k[(size_t)tok * E_ + e] = ak;
    v[(size_t)tok * E_ + e] = av;
  }
}

// ---------------------------------------------------------------------------
// Kernel 2: flash attention fp32 (unchanged math) -> bf16 ctx output
// ---------------------------------------------------------------------------
__global__ __launch_bounds__(256) void flash_attn(
    const float* __restrict__ q, const float* __restrict__ k,
    const float* __restrict__ v, __hip_bfloat16* __restrict__ ctx) {
  __shared__ float Ks[64][64];
  __shared__ float Vs[64][64];
  const int bh = blockIdx.x;
  const int b = bh >> 4, h = bh & 15;
  const int srow = blockIdx.y * 256 + threadIdx.x;
  const int t = threadIdx.x;

  float qr[64];
  {
    const float4* qrow = (const float4*)(q + (((size_t)(b * S_ + srow)) * H_ + h) * D_);
    #pragma unroll
    for (int d4 = 0; d4 < 16; d4++) {
      float4 tmp = qrow[d4];
      qr[4 * d4 + 0] = tmp.x; qr[4 * d4 + 1] = tmp.y;
      qr[4 * d4 + 2] = tmp.z; qr[4 * d4 + 3] = tmp.w;
    }
  }
  float acc[64];
  #pragma unroll
  for (int d = 0; d < 64; d++) acc[d] = 0.f;
  float m = -1e30f, l = 0.f;

  for (int kt = 0; kt < S_ / 64; kt++) {
    __syncthreads();
    #pragma unroll
    for (int r = 0; r < 4; r++) {
      const int e4 = t + r * 256;
      const int j = e4 >> 4, d4 = e4 & 15;
      const size_t base = (((size_t)(b * S_ + kt * 64 + j)) * H_ + h) * D_ + d4 * 4;
      *(float4*)&Ks[j][d4 * 4] = *(const float4*)(k + base);
      *(float4*)&Vs[j][d4 * 4] = *(const float4*)(v + base);
    }
    __syncthreads();

    for (int j = 0; j < 64; j++) {
      const float4* krow = (const float4*)Ks[j];
      float s0 = 0.f, s1 = 0.f, s2 = 0.f, s3 = 0.f;
      #pragma unroll
      for (int d4 = 0; d4 < 16; d4++) {
        float4 kk = krow[d4];
        s0 = fmaf(qr[4 * d4 + 0], kk.x, s0);
        s1 = fmaf(qr[4 * d4 + 1], kk.y, s1);
        s2 = fmaf(qr[4 * d4 + 2], kk.z, s2);
        s3 = fmaf(qr[4 * d4 + 3], kk.w, s3);
      }
      const float s = ((s0 + s1) + (s2 + s3)) * SCALE;
      const float4* vrow = (const float4*)Vs[j];
      if (s <= m) {
        const float p = __expf(s - m);
        l += p;
        #pragma unroll
        for (int d4 = 0; d4 < 16; d4++) {
          float4 vv = vrow[d4];
          acc[4 * d4 + 0] = fmaf(p, vv.x, acc[4 * d4 + 0]);
          acc[4 * d4 + 1] = fmaf(p, vv.y, acc[4 * d4 + 1]);
          acc[4 * d4 + 2] = fmaf(p, vv.z, acc[4 * d4 + 2]);
          acc[4 * d4 + 3] = fmaf(p, vv.w, acc[4 * d4 + 3]);
        }
      } else {
        const float alpha = __expf(m - s);
        m = s;
        l = fmaf(l, alpha, 1.0f);
        #pragma unroll
        for (int d4 = 0; d4 < 16; d4++) {
          float4 vv = vrow[d4];
          acc[4 * d4 + 0] = fmaf(acc[4 * d4 + 0], alpha, vv.x);
          acc[4 * d4 + 1] = fmaf(acc[4 * d4 + 1], alpha, vv.y);
          acc[4 * d4 + 2] = fmaf(acc[4 * d4 + 2], alpha, vv.z);
          acc[4 * d4 + 3] = fmaf(acc[4 * d4 + 3], alpha, vv.w);
        }
      }
    }
  }
  const float inv = 1.0f / l;
  b4s* crow = (b4s*)(ctx + (((size_t)(b * S_ + srow)) * H_ + h) * D_);
  #pragma unroll
  for (int d4 = 0; d4 < 16; d4++) {
    b4s o;
    o.x = __float2bfloat16(acc[4 * d4 + 0] * inv);
    o.y = __float2bfloat16(acc[4 * d4 + 1] * inv);
    o.z = __float2bfloat16(acc[4 * d4 + 2] * inv);
    o.w = __float2bfloat16(acc[4 * d4 + 3] * inv);
    crow[d4] = o;
  }
}

// ---------------------------------------------------------------------------
// Kernel 3: bf16 MFMA GEMM. C[M,N] = A[M,K] @ W[N,K]^T + bias (+ReLU).
// Block = 256 thr = 4 waves (2x2), block tile 128x128, wave tile 64x64
// (4x4 grid of 16x16x32 MFMA), BK=32. LDS natural [128][32] layout:
// fragment b128 reads are a perfect 64-chunk permutation (8-phase minimum).
// A and W both row-major with K contiguous -> identical fragment loads.
// ---------------------------------------------------------------------------
template <int RELU, int OUT_BF16>
__global__ __launch_bounds__(256) void gemm_mfma(
    const __hip_bfloat16* __restrict__ A, const __hip_bfloat16* __restrict__ Wt,
    const float* __restrict__ bias, void* __restrict__ Cout,
    int M, int N, int K) {
  __shared__ __bf16 As[128][32];
  __shared__ __bf16 Bs[128][32];
  const int t = threadIdx.x;
  const int lane = t & 63;
  const int w = t >> 6;
  const int wr = w >> 1, wc = w & 1;
  const int m0 = blockIdx.y * 128, n0 = blockIdx.x * 128;

  floatx4 acc[4][4] = {};

  // staging map: thread covers rows (t>>2) and (t>>2)+64, 16B chunk (t&3)
  const int srow = t >> 2;          // 0..63
  const int schunk = (t & 3) * 8;   // bf16 col offset of this 16B chunk

  const __hip_bfloat16* gA0 = A + (size_t)(m0 + srow) * K + schunk;
  const __hip_bfloat16* gA1 = A + (size_t)(m0 + srow + 64) * K + schunk;
  const __hip_bfloat16* gB0 = Wt + (size_t)(n0 + srow) * K + schunk;
  const __hip_bfloat16* gB1 = Wt + (size_t)(n0 + srow + 64) * K + schunk;

  for (int k0 = 0; k0 < K; k0 += 32) {
    bf16x8 a0 = *(const bf16x8*)(gA0 + k0);
    bf16x8 a1 = *(const bf16x8*)(gA1 + k0);
    bf16x8 b0 = *(const bf16x8*)(gB0 + k0);
    bf16x8 b1 = *(const bf16x8*)(gB1 + k0);
    __syncthreads();             // previous tile fully consumed
    *(bf16x8*)&As[srow][schunk] = a0;
    *(bf16x8*)&As[srow + 64][schunk] = a1;
    *(bf16x8*)&Bs[srow][schunk] = b0;
    *(bf16x8*)&Bs[srow + 64][schunk] = b1;
    __syncthreads();

    bf16x8 af[4], bf[4];
    #pragma unroll
    for (int i = 0; i < 4; i++) {
      af[i] = *(const bf16x8*)&As[wr * 64 + i * 16 + (lane & 15)][(lane >> 4) * 8];
      bf[i] = *(const bf16x8*)&Bs[wc * 64 + i * 16 + (lane & 15)][(lane >> 4) * 8];
    }
    #pragma unroll
    for (int mi = 0; mi < 4; mi++)
      #pragma unroll
      for (int ni = 0; ni < 4; ni++)
        acc[mi][ni] = __builtin_amdgcn_mfma_f32_16x16x32_bf16(
            af[mi], bf[ni], acc[mi][ni], 0, 0, 0);
  }

  // epilogue: C/D layout col=lane&15, row=(lane>>4)*4+reg  [m89-verified]
  const int cil = lane & 15;
  const int quad = lane >> 4;
  #pragma unroll
  for (int ni = 0; ni < 4; ni++) {
    const int col = n0 + wc * 64 + ni * 16 + cil;
    const float bb = bias[col];
    #pragma unroll
    for (int mi = 0; mi < 4; mi++) {
      const int row = m0 + wr * 64 + mi * 16 + quad * 4;
      #pragma unroll
      for (int i = 0; i < 4; i++) {
        float vv = acc[mi][ni][i] + bb;
        if (RELU) vv = fmaxf(vv, 0.f);
        if (OUT_BF16)
          ((__hip_bfloat16*)Cout)[(size_t)(row + i) * N + col] = __float2bfloat16(vv);
        else
          ((float*)Cout)[(size_t)(row + i) * N + col] = vv;
      }
    }
  }
}

// ---------------------------------------------------------------------------
// Kernel 4: out = LayerNorm(a + r)*g + b ; optional secondary bf16 output
// ---------------------------------------------------------------------------
template <int EMIT_BF16>
__global__ __launch_bounds__(256) void add_ln(
    const float* __restrict__ a, const float* __restrict__ r,
    const float* __restrict__ g, const float* __restrict__ bt,
    float* __restrict__ out, __hip_bfloat16* __restrict__ outb) {
  __shared__ float red[16];
  const int tok = blockIdx.x, t = threadIdx.x;
  float4 av = ((const float4*)(a + (size_t)tok * E_))[t];
  float4 rv = ((const float4*)(r + (size_t)tok * E_))[t];
  float4 x;
  x.x = av.x + rv.x; x.y = av.y + rv.y; x.z = av.z + rv.z; x.w = av.w + rv.w;
  float sum = x.x + x.y + x.z + x.w;
  float ssq = x.x * x.x + x.y * x.y + x.z * x.z + x.w * x.w;
  #pragma unroll
  for (int off = 32; off >= 1; off >>= 1) {
    sum += __shfl_down(sum, off, 64);
    ssq += __shfl_down(ssq, off, 64);
  }
  const int wave = t >> 6;
  if ((t & 63) == 0) { red[wave] = sum; red[4 + wave] = ssq; }
  __syncthreads();
  if (t == 0) {
    float s = red[0] + red[1] + red[2] + red[3];
    float qq = red[4] + red[5] + red[6] + red[7];
    float mu = s * (1.0f / E_);
    red[8] = mu;
    red[9] = qq * (1.0f / E_) - mu * mu;
  }
  __syncthreads();
  const float mu = red[8];
  const float inv = rsqrtf(red[9] + 1e-5f);
  float4 gv = ((const float4*)g)[t];
  float4 bv = ((const float4*)bt)[t];
  float4 o;
  o.x = (x.x - mu) * inv * gv.x + bv.x;
  o.y = (x.y - mu) * inv * gv.y + bv.y;
  o.z = (x.z - mu) * inv * gv.z + bv.z;
  o.w = (x.w - mu) * inv * gv.w + bv.w;
  ((float4*)(out + (size_t)tok * E_))[t] = o;
  if (EMIT_BF16) {
    b4s ob;
    ob.x = __float2bfloat16(o.x); ob.y = __float2bfloat16(o.y);
    ob.z = __float2bfloat16(o.z); ob.w = __float2bfloat16(o.w);
    *(b4s*)(outb + (size_t)tok * E_ + t * 4) = ob;
  }
}

// ---------------------------------------------------------------------------
extern "C" void kernel_launch(void* const* d_in, const int* in_sizes, int n_in,
                              void* d_out, int out_size, void* d_ws, size_t ws_size,
                              hipStream_t stream) {
  const float* queries = (const float*)d_in[0];
  const float* keys    = (const float*)d_in[1];
  const float* values  = (const float*)d_in[2];
  const float* Wq  = (const float*)d_in[4];
  const float* Wk  = (const float*)d_in[5];
  const float* Wv  = (const float*)d_in[6];
  const float* Wfc = (const float*)d_in[7];
  const float* bfc = (const float*)d_in[8];
  const float* W1  = (const float*)d_in[9];
  const float* b1  = (const float*)d_in[10];
  const float* W2  = (const float*)d_in[11];
  const float* b2  = (const float*)d_in[12];
  const float* ln1_g = (const float*)d_in[13];
  const float* ln1_b = (const float*)d_in[14];
  const float* ln2_g = (const float*)d_in[15];
  const float* ln2_b = (const float*)d_in[16];

  const size_t M4 = 4194304;   // 4M floats
  float* ws = (float*)d_ws;
  float* Q  = ws;
  float* Kf = ws + M4;
  float* Vf = ws + 2 * M4;
  // bf16 region starts at ws + 3*M4 floats
  __hip_bfloat16* bbase = (__hip_bfloat16*)(ws + 3 * M4);
  __hip_bfloat16* CTXb = bbase;                 //  4M elems
  __hip_bfloat16* Hb   = CTXb + M4;             //  4M
  __hip_bfloat16* FF1b = Hb + M4;               // 16M
  __hip_bfloat16* Wfcb = FF1b + 4 * M4;         //  1M
  __hip_bfloat16* W1b  = Wfcb + M4 / 4;         //  4M
  __hip_bfloat16* W2b  = W1b + M4;              //  4M
  float* ATT = Q;    // Q dead after attention
  float* Hf  = Kf;   // K dead after attention
  float* X   = Vf;   // V dead after attention
  float* out = (float*)d_out;

  // weight casts (independent of everything upstream)
  cast_f2b<<<(E_ * E_ / 4 + 255) / 256, 256, 0, stream>>>(Wfc, Wfcb, E_ * E_ / 4);
  cast_f2b<<<(4 * E_ * E_ / 4 + 255) / 256, 256, 0, stream>>>(W1, W1b, 4 * E_ * E_ / 4);
  cast_f2b<<<(4 * E_ * E_ / 4 + 255) / 256, 256, 0, stream>>>(W2, W2b, 4 * E_ * E_ / 4);

  qkv_proj<<<TOK, 256, 0, stream>>>(queries, keys, values, Wq, Wk, Wv, Q, Kf, Vf);
  flash_attn<<<dim3(B_ * H_, S_ / 256), 256, 0, stream>>>(Q, Kf, Vf, CTXb);
  gemm_mfma<0, 0><<<dim3(E_ / 128, TOK / 128), 256, 0, stream>>>(
      CTXb, Wfcb, bfc, ATT, TOK, E_, E_);
  add_ln<1><<<TOK, 256, 0, stream>>>(ATT, queries, ln1_g, ln1_b, Hf, Hb);
  gemm_mfma<1, 1><<<dim3(4 * E_ / 128, TOK / 128), 256, 0, stream>>>(
      Hb, W1b, b1, FF1b, TOK, 4 * E_, E_);
  gemm_mfma<0, 0><<<dim3(E_ / 128, TOK / 128), 256, 0, stream>>>(
      FF1b, W2b, b2, X, TOK, E_, 4 * E_);
  add_ln<0><<<TOK, 256, 0, stream>>>(X, Hf, ln2_g, ln2_b, out, nullptr);
}

// Round 3
// 1209.435 us; speedup vs baseline: 2.9502x; 2.1130x over previous
//
#include <hip/hip_runtime.h>
#include <hip/hip_bf16.h>
#include <math.h>

#define B_ 2
#define S_ 2048
#define E_ 1024
#define H_ 16
#define D_ 64
#define TOK (B_*S_)          // 4096 tokens
#define SCALE 45.254833995939045f   // sqrt(2048): reference's softmax(scores / S**-0.5)

typedef __bf16 bf16x8 __attribute__((ext_vector_type(8)));
typedef float floatx4 __attribute__((ext_vector_type(4)));
struct b4s { __hip_bfloat16 x, y, z, w; };   // 8-byte packed bf16 quad

// ---------------------------------------------------------------------------
// fp32 -> bf16 cast (for weights)
// ---------------------------------------------------------------------------
__global__ __launch_bounds__(256) void cast_f2b(
    const float* __restrict__ in, __hip_bfloat16* __restrict__ out, int n4) {
  int i = blockIdx.x * 256 + threadIdx.x;
  if (i < n4) {
    float4 v = ((const float4*)in)[i];
    b4s o;
    o.x = __float2bfloat16(v.x); o.y = __float2bfloat16(v.y);
    o.z = __float2bfloat16(v.z); o.w = __float2bfloat16(v.w);
    *(b4s*)(out + (size_t)i * 4) = o;
  }
}

// ---------------------------------------------------------------------------
// Kernel 1: per-head QKV projection (fp32, unchanged)
// ---------------------------------------------------------------------------
__global__ __launch_bounds__(256) void qkv_proj(
    const float* __restrict__ xq, const float* __restrict__ xk,
    const float* __restrict__ xv,
    const float* __restrict__ Wq, const float* __restrict__ Wk,
    const float* __restrict__ Wv,
    float* __restrict__ q, float* __restrict__ k, float* __restrict__ v) {
  __shared__ float lx0[E_], lx1[E_], lx2[E_];
  const int tok = blockIdx.x;
  const int t = threadIdx.x;
  ((float4*)lx0)[t] = ((const float4*)(xq + (size_t)tok * E_))[t];
  ((float4*)lx1)[t] = ((const float4*)(xk + (size_t)tok * E_))[t];
  ((float4*)lx2)[t] = ((const float4*)(xv + (size_t)tok * E_))[t];
  __syncthreads();
  #pragma unroll
  for (int rep = 0; rep < 4; rep++) {
    const int e = t + rep * 256;
    const int hh = e >> 6, rr = e & 63;
    const float4* wq4 = (const float4*)(Wq + rr * D_);
    const float4* wk4 = (const float4*)(Wk + rr * D_);
    const float4* wv4 = (const float4*)(Wv + rr * D_);
    const float4* lq4 = (const float4*)(&lx0[hh * D_]);
    const float4* lk4 = (const float4*)(&lx1[hh * D_]);
    const float4* lv4 = (const float4*)(&lx2[hh * D_]);
    float aq = 0.f, ak = 0.f, av = 0.f;
    #pragma unroll
    for (int d4 = 0; d4 < 16; d4++) {
      float4 w, x;
      w = wq4[d4]; x = lq4[d4];
      aq = fmaf(w.x, x.x, aq); aq = fmaf(w.y, x.y, aq);
      aq = fmaf(w.z, x.z, aq); aq = fmaf(w.w, x.w, aq);
      w = wk4[d4]; x = lk4[d4];
      ak = fmaf(w.x, x.x, ak); ak = fmaf(w.y, x.y, ak);
      ak = fmaf(w.z, x.z, ak); ak = fmaf(w.w, x.w, ak);
      w = wv4[d4]; x = lv4[d4];
      av = fmaf(w.x, x.x, av); av = fmaf(w.y, x.y, av);
      av = fmaf(w.z, x.z, av); av = fmaf(w.w, x.w, av);
    }
    q[(size_t)tok * E_ + e] = aq;
    k[(size_t)tok * E_ + e] = ak;
    v[(size_t)tok * E_ + e] = av;
  }
}

// ---------------------------------------------------------------------------
// Kernel 2a: hi/lo bf16 split of Q and K, relayout [tok][E] -> [bh][s][d].
// hi = bf16(x); lo = bf16(x - hi)  (exact two-term split).
// ---------------------------------------------------------------------------
__global__ __launch_bounds__(256) void split_hl(
    const float* __restrict__ q, const float* __restrict__ k,
    __hip_bfloat16* __restrict__ qhi, __hip_bfloat16* __restrict__ qlo,
    __hip_bfloat16* __restrict__ khi, __hip_bfloat16* __restrict__ klo) {
  const int tok = blockIdx.x, t = threadIdx.x;
  const int b = tok >> 11, s = tok & 2047;
  const int h = t >> 4, d = (4 * t) & 63;
  const size_t dst = ((size_t)(b * H_ + h) * S_ + s) * 64 + d;
  {
    float4 x = ((const float4*)(q + (size_t)tok * E_))[t];
    b4s hi, lo;
    hi.x = __float2bfloat16(x.x); lo.x = __float2bfloat16(x.x - __bfloat162float(hi.x));
    hi.y = __float2bfloat16(x.y); lo.y = __float2bfloat16(x.y - __bfloat162float(hi.y));
    hi.z = __float2bfloat16(x.z); lo.z = __float2bfloat16(x.z - __bfloat162float(hi.z));
    hi.w = __float2bfloat16(x.w); lo.w = __float2bfloat16(x.w - __bfloat162float(hi.w));
    *(b4s*)(qhi + dst) = hi; *(b4s*)(qlo + dst) = lo;
  }
  {
    float4 x = ((const float4*)(k + (size_t)tok * E_))[t];
    b4s hi, lo;
    hi.x = __float2bfloat16(x.x); lo.x = __float2bfloat16(x.x - __bfloat162float(hi.x));
    hi.y = __float2bfloat16(x.y); lo.y = __float2bfloat16(x.y - __bfloat162float(hi.y));
    hi.z = __float2bfloat16(x.z); lo.z = __float2bfloat16(x.z - __bfloat162float(hi.z));
    hi.w = __float2bfloat16(x.w); lo.w = __float2bfloat16(x.w - __bfloat162float(hi.w));
    *(b4s*)(khi + dst) = hi; *(b4s*)(klo + dst) = lo;
  }
}

// ---------------------------------------------------------------------------
// Kernel 2b: V fp32 [tok][E] -> bf16 V^T [bh][d][s]  (LDS-tiled transpose)
// ---------------------------------------------------------------------------
__global__ __launch_bounds__(256) void transpose_v(
    const float* __restrict__ v, __hip_bfloat16* __restrict__ vt) {
  __shared__ float T[64][68];
  const int bh = blockIdx.y, s0 = blockIdx.x * 64;
  const int b = bh >> 4, h = bh & 15;
  const int t = threadIdx.x;
  const int r = t >> 2, c0 = (t & 3) * 16;
  const float* src = v + ((size_t)(b * S_ + s0 + r)) * E_ + h * 64 + c0;
  #pragma unroll
  for (int i = 0; i < 4; i++)
    *(float4*)&T[r][c0 + 4 * i] = *(const float4*)(src + 4 * i);
  __syncthreads();
  // thread writes row d = t>>2, s-chunk (t&3)*16
  const int d = t >> 2, sc = (t & 3) * 16;
  __hip_bfloat16* dst = vt + ((size_t)bh * 64 + d) * S_ + s0 + sc;
  #pragma unroll
  for (int i = 0; i < 4; i++) {
    b4s o;
    o.x = __float2bfloat16(T[sc + 4 * i + 0][d]);
    o.y = __float2bfloat16(T[sc + 4 * i + 1][d]);
    o.z = __float2bfloat16(T[sc + 4 * i + 2][d]);
    o.w = __float2bfloat16(T[sc + 4 * i + 3][d]);
    *(b4s*)(dst + 4 * i) = o;
  }
}

// ---------------------------------------------------------------------------
// Kernel 2c: MFMA flash attention.
// grid = (S/64 q-tiles, B*H). Block = 256 thr = 4 waves; wave w owns q rows
// [w*16, w*16+16). Scores via split-bf16 QK^T (3 products, fp32-grade logits),
// online softmax in C-layout with 16-lane shfl_xor row reductions, P through
// per-wave LDS into A-layout, PV via bf16 MFMA against V^T tiles.
// All LDS tiles use the round-2-validated [rows][32] chunk addressing.
// ---------------------------------------------------------------------------
__global__ __launch_bounds__(256) void attn_mfma(
    const __hip_bfloat16* __restrict__ Qhi, const __hip_bfloat16* __restrict__ Qlo,
    const __hip_bfloat16* __restrict__ Khi, const __hip_bfloat16* __restrict__ Klo,
    const __hip_bfloat16* __restrict__ Vtg, __hip_bfloat16* __restrict__ ctx) {
  __shared__ __bf16 Qh[2][64][32], Ql[2][64][32];
  __shared__ __bf16 Kh[2][64][32], Kl[2][64][32];
  __shared__ __bf16 Vs[2][64][32];
  __shared__ __bf16 Ps[4][2][16][32];
  const int t = threadIdx.x, lane = t & 63, w = t >> 6;
  const int quad = lane >> 4, low = lane & 15;
  const int bh = blockIdx.y;
  const int q0 = blockIdx.x * 64;

  const int sr = t >> 2;            // staging row 0..63
  const int sc = (t & 3) * 16;      // bf16 col {0,16,32,48}
  const int scc = sc >> 5, sco = sc & 31;

  { // stage Q tile once
    const size_t g = ((size_t)bh * S_ + q0 + sr) * 64 + sc;
    bf16x8 h0 = *(const bf16x8*)(Qhi + g);
    bf16x8 h1 = *(const bf16x8*)(Qhi + g + 8);
    bf16x8 l0 = *(const bf16x8*)(Qlo + g);
    bf16x8 l1 = *(const bf16x8*)(Qlo + g + 8);
    *(bf16x8*)&Qh[scc][sr][sco] = h0; *(bf16x8*)&Qh[scc][sr][sco + 8] = h1;
    *(bf16x8*)&Ql[scc][sr][sco] = l0; *(bf16x8*)&Ql[scc][sr][sco + 8] = l1;
  }
  __syncthreads();
  bf16x8 qh[2], ql[2];
  #pragma unroll
  for (int c = 0; c < 2; c++) {
    qh[c] = *(const bf16x8*)&Qh[c][w * 16 + low][quad * 8];
    ql[c] = *(const bf16x8*)&Ql[c][w * 16 + low][quad * 8];
  }

  floatx4 oacc[4] = {};
  float mrow[4], lrow[4];
  #pragma unroll
  for (int i = 0; i < 4; i++) { mrow[i] = -1e30f; lrow[i] = 0.f; }

  for (int kt = 0; kt < S_ / 64; kt++) {
    const size_t gk = ((size_t)bh * S_ + kt * 64 + sr) * 64 + sc;
    const size_t gv = ((size_t)bh * 64 + sr) * S_ + kt * 64 + sc;
    bf16x8 kh0 = *(const bf16x8*)(Khi + gk);
    bf16x8 kh1 = *(const bf16x8*)(Khi + gk + 8);
    bf16x8 kl0 = *(const bf16x8*)(Klo + gk);
    bf16x8 kl1 = *(const bf16x8*)(Klo + gk + 8);
    bf16x8 vv0 = *(const bf16x8*)(Vtg + gv);
    bf16x8 vv1 = *(const bf16x8*)(Vtg + gv + 8);
    __syncthreads();                       // prior tile fully consumed
    *(bf16x8*)&Kh[scc][sr][sco] = kh0; *(bf16x8*)&Kh[scc][sr][sco + 8] = kh1;
    *(bf16x8*)&Kl[scc][sr][sco] = kl0; *(bf16x8*)&Kl[scc][sr][sco + 8] = kl1;
    *(bf16x8*)&Vs[scc][sr][sco] = vv0; *(bf16x8*)&Vs[scc][sr][sco + 8] = vv1;
    __syncthreads();

    // ---- scores: 4 ntiles x (3 split products x 2 d-chunks) ----
    floatx4 sa[4];
    #pragma unroll
    for (int nn = 0; nn < 4; nn++) {
      bf16x8 kh[2], kl[2];
      #pragma unroll
      for (int c = 0; c < 2; c++) {
        kh[c] = *(const bf16x8*)&Kh[c][nn * 16 + low][quad * 8];
        kl[c] = *(const bf16x8*)&Kl[c][nn * 16 + low][quad * 8];
      }
      floatx4 s = {};
      s = __builtin_amdgcn_mfma_f32_16x16x32_bf16(qh[0], kh[0], s, 0, 0, 0);
      s = __builtin_amdgcn_mfma_f32_16x16x32_bf16(qh[1], kh[1], s, 0, 0, 0);
      s = __builtin_amdgcn_mfma_f32_16x16x32_bf16(ql[0], kh[0], s, 0, 0, 0);
      s = __builtin_amdgcn_mfma_f32_16x16x32_bf16(ql[1], kh[1], s, 0, 0, 0);
      s = __builtin_amdgcn_mfma_f32_16x16x32_bf16(qh[0], kl[0], s, 0, 0, 0);
      s = __builtin_amdgcn_mfma_f32_16x16x32_bf16(qh[1], kl[1], s, 0, 0, 0);
      sa[nn] = s;
    }

    // ---- online softmax; lane's rows are q_local = quad*4+i ----
    float pv[4][4];
    #pragma unroll
    for (int i = 0; i < 4; i++) {
      float s0 = sa[0][i] * SCALE, s1 = sa[1][i] * SCALE;
      float s2 = sa[2][i] * SCALE, s3 = sa[3][i] * SCALE;
      float rmax = fmaxf(fmaxf(s0, s1), fmaxf(s2, s3));
      rmax = fmaxf(rmax, __shfl_xor(rmax, 1, 64));
      rmax = fmaxf(rmax, __shfl_xor(rmax, 2, 64));
      rmax = fmaxf(rmax, __shfl_xor(rmax, 4, 64));
      rmax = fmaxf(rmax, __shfl_xor(rmax, 8, 64));
      const float nm = fmaxf(mrow[i], rmax);
      const float al = __expf(mrow[i] - nm);
      mrow[i] = nm;
      const float p0 = __expf(s0 - nm), p1 = __expf(s1 - nm);
      const float p2 = __expf(s2 - nm), p3 = __expf(s3 - nm);
      pv[0][i] = p0; pv[1][i] = p1; pv[2][i] = p2; pv[3][i] = p3;
      float rs = (p0 + p1) + (p2 + p3);
      rs += __shfl_xor(rs, 1, 64);
      rs += __shfl_xor(rs, 2, 64);
      rs += __shfl_xor(rs, 4, 64);
      rs += __shfl_xor(rs, 8, 64);
      lrow[i] = lrow[i] * al + rs;
      oacc[0][i] *= al; oacc[1][i] *= al; oacc[2][i] *= al; oacc[3][i] *= al;
    }

    // ---- P: C-layout -> A-layout via per-wave LDS ----
    #pragma unroll
    for (int nn = 0; nn < 4; nn++)
      #pragma unroll
      for (int i = 0; i < 4; i++)
        Ps[w][nn >> 1][quad * 4 + i][(nn & 1) * 16 + low] = (__bf16)pv[nn][i];
    bf16x8 pa0 = *(const bf16x8*)&Ps[w][0][low][quad * 8];
    bf16x8 pa1 = *(const bf16x8*)&Ps[w][1][low][quad * 8];

    // ---- PV ----
    #pragma unroll
    for (int dt = 0; dt < 4; dt++) {
      bf16x8 vb0 = *(const bf16x8*)&Vs[0][dt * 16 + low][quad * 8];
      bf16x8 vb1 = *(const bf16x8*)&Vs[1][dt * 16 + low][quad * 8];
      oacc[dt] = __builtin_amdgcn_mfma_f32_16x16x32_bf16(pa0, vb0, oacc[dt], 0, 0, 0);
      oacc[dt] = __builtin_amdgcn_mfma_f32_16x16x32_bf16(pa1, vb1, oacc[dt], 0, 0, 0);
    }
  }

  // ---- epilogue: ctx[tok][E] bf16, row=q0+w*16+quad*4+i, col=h*64+dt*16+low
  const int b = bh >> 4, h = bh & 15;
  #pragma unroll
  for (int i = 0; i < 4; i++) {
    const float inv = 1.0f / lrow[i];
    const int row = q0 + w * 16 + quad * 4 + i;
    const size_t base = ((size_t)(b * S_ + row)) * E_ + h * 64 + low;
    #pragma unroll
    for (int dt = 0; dt < 4; dt++)
      ctx[base + dt * 16] = __float2bfloat16(oacc[dt][i] * inv);
  }
}

// ---------------------------------------------------------------------------
// Kernel 3: bf16 MFMA GEMM (unchanged from round 2)
// ---------------------------------------------------------------------------
template <int RELU, int OUT_BF16>
__global__ __launch_bounds__(256) void gemm_mfma(
    const __hip_bfloat16* __restrict__ A, const __hip_bfloat16* __restrict__ Wt,
    const float* __restrict__ bias, void* __restrict__ Cout,
    int M, int N, int K) {
  __shared__ __bf16 As[128][32];
  __shared__ __bf16 Bs[128][32];
  const int t = threadIdx.x;
  const int lane = t & 63;
  const int w = t >> 6;
  const int wr = w >> 1, wc = w & 1;
  const int m0 = blockIdx.y * 128, n0 = blockIdx.x * 128;

  floatx4 acc[4][4] = {};
  const int srow = t >> 2;
  const int schunk = (t & 3) * 8;

  const __hip_bfloat16* gA0 = A + (size_t)(m0 + srow) * K + schunk;
  const __hip_bfloat16* gA1 = A + (size_t)(m0 + srow + 64) * K + schunk;
  const __hip_bfloat16* gB0 = Wt + (size_t)(n0 + srow) * K + schunk;
  const __hip_bfloat16* gB1 = Wt + (size_t)(n0 + srow + 64) * K + schunk;

  for (int k0 = 0; k0 < K; k0 += 32) {
    bf16x8 a0 = *(const bf16x8*)(gA0 + k0);
    bf16x8 a1 = *(const bf16x8*)(gA1 + k0);
    bf16x8 b0 = *(const bf16x8*)(gB0 + k0);
    bf16x8 b1 = *(const bf16x8*)(gB1 + k0);
    __syncthreads();
    *(bf16x8*)&As[srow][schunk] = a0;
    *(bf16x8*)&As[srow + 64][schunk] = a1;
    *(bf16x8*)&Bs[srow][schunk] = b0;
    *(bf16x8*)&Bs[srow + 64][schunk] = b1;
    __syncthreads();

    bf16x8 af[4], bf[4];
    #pragma unroll
    for (int i = 0; i < 4; i++) {
      af[i] = *(const bf16x8*)&As[wr * 64 + i * 16 + (lane & 15)][(lane >> 4) * 8];
      bf[i] = *(const bf16x8*)&Bs[wc * 64 + i * 16 + (lane & 15)][(lane >> 4) * 8];
    }
    #pragma unroll
    for (int mi = 0; mi < 4; mi++)
      #pragma unroll
      for (int ni = 0; ni < 4; ni++)
        acc[mi][ni] = __builtin_amdgcn_mfma_f32_16x16x32_bf16(
            af[mi], bf[ni], acc[mi][ni], 0, 0, 0);
  }

  const int cil = lane & 15;
  const int quad = lane >> 4;
  #pragma unroll
  for (int ni = 0; ni < 4; ni++) {
    const int col = n0 + wc * 64 + ni * 16 + cil;
    const float bb = bias[col];
    #pragma unroll
    for (int mi = 0; mi < 4; mi++) {
      const int row = m0 + wr * 64 + mi * 16 + quad * 4;
      #pragma unroll
      for (int i = 0; i < 4; i++) {
        float vv = acc[mi][ni][i] + bb;
        if (RELU) vv = fmaxf(vv, 0.f);
        if (OUT_BF16)
          ((__hip_bfloat16*)Cout)[(size_t)(row + i) * N + col] = __float2bfloat16(vv);
        else
          ((float*)Cout)[(size_t)(row + i) * N + col] = vv;
      }
    }
  }
}

// ---------------------------------------------------------------------------
// Kernel 4: out = LayerNorm(a + r)*g + b ; optional secondary bf16 output
// ---------------------------------------------------------------------------
template <int EMIT_BF16>
__global__ __launch_bounds__(256) void add_ln(
    const float* __restrict__ a, const float* __restrict__ r,
    const float* __restrict__ g, const float* __restrict__ bt,
    float* __restrict__ out, __hip_bfloat16* __restrict__ outb) {
  __shared__ float red[16];
  const int tok = blockIdx.x, t = threadIdx.x;
  float4 av = ((const float4*)(a + (size_t)tok * E_))[t];
  float4 rv = ((const float4*)(r + (size_t)tok * E_))[t];
  float4 x;
  x.x = av.x + rv.x; x.y = av.y + rv.y; x.z = av.z + rv.z; x.w = av.w + rv.w;
  float sum = x.x + x.y + x.z + x.w;
  float ssq = x.x * x.x + x.y * x.y + x.z * x.z + x.w * x.w;
  #pragma unroll
  for (int off = 32; off >= 1; off >>= 1) {
    sum += __shfl_down(sum, off, 64);
    ssq += __shfl_down(ssq, off, 64);
  }
  const int wave = t >> 6;
  if ((t & 63) == 0) { red[wave] = sum; red[4 + wave] = ssq; }
  __syncthreads();
  if (t == 0) {
    float s = red[0] + red[1] + red[2] + red[3];
    float qq = red[4] + red[5] + red[6] + red[7];
    float mu = s * (1.0f / E_);
    red[8] = mu;
    red[9] = qq * (1.0f / E_) - mu * mu;
  }
  __syncthreads();
  const float mu = red[8];
  const float inv = rsqrtf(red[9] + 1e-5f);
  float4 gv = ((const float4*)g)[t];
  float4 bv = ((const float4*)bt)[t];
  float4 o;
  o.x = (x.x - mu) * inv * gv.x + bv.x;
  o.y = (x.y - mu) * inv * gv.y + bv.y;
  o.z = (x.z - mu) * inv * gv.z + bv.z;
  o.w = (x.w - mu) * inv * gv.w + bv.w;
  ((float4*)(out + (size_t)tok * E_))[t] = o;
  if (EMIT_BF16) {
    b4s ob;
    ob.x = __float2bfloat16(o.x); ob.y = __float2bfloat16(o.y);
    ob.z = __float2bfloat16(o.z); ob.w = __float2bfloat16(o.w);
    *(b4s*)(outb + (size_t)tok * E_ + t * 4) = ob;
  }
}

// ---------------------------------------------------------------------------
extern "C" void kernel_launch(void* const* d_in, const int* in_sizes, int n_in,
                              void* d_out, int out_size, void* d_ws, size_t ws_size,
                              hipStream_t stream) {
  const float* queries = (const float*)d_in[0];
  const float* keys    = (const float*)d_in[1];
  const float* values  = (const float*)d_in[2];
  const float* Wq  = (const float*)d_in[4];
  const float* Wk  = (const float*)d_in[5];
  const float* Wv  = (const float*)d_in[6];
  const float* Wfc = (const float*)d_in[7];
  const float* bfc = (const float*)d_in[8];
  const float* W1  = (const float*)d_in[9];
  const float* b1  = (const float*)d_in[10];
  const float* W2  = (const float*)d_in[11];
  const float* b2  = (const float*)d_in[12];
  const float* ln1_g = (const float*)d_in[13];
  const float* ln1_b = (const float*)d_in[14];
  const float* ln2_g = (const float*)d_in[15];
  const float* ln2_b = (const float*)d_in[16];

  const size_t M1 = 1048576;
  float* ws = (float*)d_ws;
  float* Qf = ws;              // 4M fl
  float* Kf = ws + 4 * M1;     // 4M fl
  float* Vf = ws + 8 * M1;     // 4M fl
  __hip_bfloat16* bb = (__hip_bfloat16*)(ws + 12 * M1);
  __hip_bfloat16* CTXb = bb;                  //  4M
  __hip_bfloat16* Hb   = bb + 4 * M1;         //  4M
  __hip_bfloat16* Wfcb = bb + 8 * M1;         //  1M
  __hip_bfloat16* W1b  = bb + 9 * M1;         //  4M
  __hip_bfloat16* W2b  = bb + 13 * M1;        //  4M
  // attention temps (17M..37M) alias FF1b (17M..33M): FF1b written after attn
  __hip_bfloat16* Qhi  = bb + 17 * M1;        //  4M
  __hip_bfloat16* Qlo  = bb + 21 * M1;        //  4M
  __hip_bfloat16* Khi  = bb + 25 * M1;        //  4M
  __hip_bfloat16* Klo  = bb + 29 * M1;        //  4M
  __hip_bfloat16* Vtb  = bb + 33 * M1;        //  4M
  __hip_bfloat16* FF1b = bb + 17 * M1;        // 16M (after attention)
  float* ATT = Qf;   // Q dead after attention
  float* Hf  = Kf;   // K dead after attention
  float* X   = Vf;   // V dead after attention
  float* out = (float*)d_out;

  cast_f2b<<<(E_ * E_ / 4 + 255) / 256, 256, 0, stream>>>(Wfc, Wfcb, E_ * E_ / 4);
  cast_f2b<<<(4 * E_ * E_ / 4 + 255) / 256, 256, 0, stream>>>(W1, W1b, 4 * E_ * E_ / 4);
  cast_f2b<<<(4 * E_ * E_ / 4 + 255) / 256, 256, 0, stream>>>(W2, W2b, 4 * E_ * E_ / 4);

  qkv_proj<<<TOK, 256, 0, stream>>>(queries, keys, values, Wq, Wk, Wv, Qf, Kf, Vf);
  split_hl<<<TOK, 256, 0, stream>>>(Qf, Kf, Qhi, Qlo, Khi, Klo);
  transpose_v<<<dim3(S_ / 64, B_ * H_), 256, 0, stream>>>(Vf, Vtb);
  attn_mfma<<<dim3(S_ / 64, B_ * H_), 256, 0, stream>>>(Qhi, Qlo, Khi, Klo, Vtb, CTXb);
  gemm_mfma<0, 0><<<dim3(E_ / 128, TOK / 128), 256, 0, stream>>>(
      CTXb, Wfcb, bfc, ATT, TOK, E_, E_);
  add_ln<1><<<TOK, 256, 0, stream>>>(ATT, queries, ln1_g, ln1_b, Hf, Hb);
  gemm_mfma<1, 1><<<dim3(4 * E_ / 128, TOK / 128), 256, 0, stream>>>(
      Hb, W1b, b1, FF1b, TOK, 4 * E_, E_);
  gemm_mfma<0, 0><<<dim3(E_ / 128, TOK / 128), 256, 0, stream>>>(
      FF1b, W2b, b2, X, TOK, E_, 4 * E_);
  add_ln<0><<<TOK, 256, 0, stream>>>(X, Hf, ln2_g, ln2_b, out, nullptr);
}

// Round 4
// 531.643 us; speedup vs baseline: 6.7113x; 2.2749x over previous
//
#include <hip/hip_runtime.h>
#include <hip/hip_bf16.h>
#include <math.h>

#define B_ 2
#define S_ 2048
#define E_ 1024
#define H_ 16
#define D_ 64
#define TOK (B_*S_)          // 4096 tokens
#define SCALE 45.254833995939045f   // sqrt(2048): reference's softmax(scores / S**-0.5)

typedef __bf16 bf16x8 __attribute__((ext_vector_type(8)));
typedef float floatx4 __attribute__((ext_vector_type(4)));
struct b4s { __hip_bfloat16 x, y, z, w; };   // 8-byte packed bf16 quad

// ---------------------------------------------------------------------------
// fp32 -> bf16 cast (for big weights)
// ---------------------------------------------------------------------------
__global__ __launch_bounds__(256) void cast_f2b(
    const float* __restrict__ in, __hip_bfloat16* __restrict__ out, int n4) {
  int i = blockIdx.x * 256 + threadIdx.x;
  if (i < n4) {
    float4 v = ((const float4*)in)[i];
    b4s o;
    o.x = __float2bfloat16(v.x); o.y = __float2bfloat16(v.y);
    o.z = __float2bfloat16(v.z); o.w = __float2bfloat16(v.w);
    *(b4s*)(out + (size_t)i * 4) = o;
  }
}

// ---------------------------------------------------------------------------
// Wq/Wk/Wv (64x64 fp32 each) -> hi/lo bf16 split, layout [m][2][4096].
// grid 12 x 256, each thread 4 elements.
// ---------------------------------------------------------------------------
__global__ __launch_bounds__(256) void cast_whl(
    const float* __restrict__ Wq, const float* __restrict__ Wk,
    const float* __restrict__ Wv, __hip_bfloat16* __restrict__ Whl) {
  const int idx = blockIdx.x * 256 + threadIdx.x;   // 0..3071
  const int m = idx >> 10;
  const int off = (idx & 1023) * 4;
  const float* W = (m == 0) ? Wq : (m == 1) ? Wk : Wv;
  float4 v = *(const float4*)(W + off);
  b4s hi, lo;
  hi.x = __float2bfloat16(v.x); lo.x = __float2bfloat16(v.x - __bfloat162float(hi.x));
  hi.y = __float2bfloat16(v.y); lo.y = __float2bfloat16(v.y - __bfloat162float(hi.y));
  hi.z = __float2bfloat16(v.z); lo.z = __float2bfloat16(v.z - __bfloat162float(hi.z));
  hi.w = __float2bfloat16(v.w); lo.w = __float2bfloat16(v.w - __bfloat162float(hi.w));
  *(b4s*)(Whl + (size_t)m * 8192 + off) = hi;
  *(b4s*)(Whl + (size_t)m * 8192 + 4096 + off) = lo;
}

// ---------------------------------------------------------------------------
// Fused QKV projection + hi/lo split + V transpose (MFMA, split-bf16).
// grid = (S/64 token tiles, B*H). Block = 256 thr = 4 waves; wave w owns
// tokens [w*16, w*16+16). For each of q/k/v: stage the 64x64 input slice
// (hi/lo bf16) in the attn-validated [2][64][32] layout, 3-product split
// MFMA against W (hi/lo fragments straight from L1), then:
//   q,k: hi/lo split of the fp32 accumulator -> Qhi/Qlo/Khi/Klo [bh][s][d]
//   v:   LDS transpose -> Vt [bh][d][s] bf16
// ---------------------------------------------------------------------------
__global__ __launch_bounds__(256) void qkv_fused(
    const float* __restrict__ xq, const float* __restrict__ xk,
    const float* __restrict__ xv, const __hip_bfloat16* __restrict__ Whl,
    __hip_bfloat16* __restrict__ qhi, __hip_bfloat16* __restrict__ qlo,
    __hip_bfloat16* __restrict__ khi, __hip_bfloat16* __restrict__ klo,
    __hip_bfloat16* __restrict__ vt) {
  __shared__ __bf16 Xh[2][64][32], Xl[2][64][32];
  __shared__ __bf16 Vt[64][72];   // pad 72: 144B row stride (16B mult), <=2-way write conflicts
  const int t = threadIdx.x, lane = t & 63, w = t >> 6;
  const int quad = lane >> 4, low = lane & 15;
  const int bh = blockIdx.y;
  const int b = bh >> 4, h = bh & 15;
  const int s0 = blockIdx.x * 64;
  const int sr = t >> 2;           // staging row 0..63
  const int sc = (t & 3) * 16;     // staging col {0,16,32,48}
  const int scc = sc >> 5, sco = sc & 31;

  for (int m = 0; m < 3; m++) {
    const float* xin = (m == 0) ? xq : (m == 1) ? xk : xv;
    const __hip_bfloat16* Wh = Whl + (size_t)m * 8192;

    __syncthreads();   // previous pass's fragment loads complete
    { // stage 64x64 fp32 slice -> hi/lo bf16 LDS
      const float* src = xin + ((size_t)(b * S_ + s0 + sr)) * E_ + h * 64 + sc;
      float4 f0 = *(const float4*)(src);
      float4 f1 = *(const float4*)(src + 4);
      float4 f2 = *(const float4*)(src + 8);
      float4 f3 = *(const float4*)(src + 12);
      float fv[16] = {f0.x, f0.y, f0.z, f0.w, f1.x, f1.y, f1.z, f1.w,
                      f2.x, f2.y, f2.z, f2.w, f3.x, f3.y, f3.z, f3.w};
      bf16x8 hi0, hi1, lo0, lo1;
      #pragma unroll
      for (int j = 0; j < 8; j++) {
        hi0[j] = (__bf16)fv[j];
        lo0[j] = (__bf16)(fv[j] - (float)hi0[j]);
        hi1[j] = (__bf16)fv[8 + j];
        lo1[j] = (__bf16)(fv[8 + j] - (float)hi1[j]);
      }
      *(bf16x8*)&Xh[scc][sr][sco] = hi0;
      *(bf16x8*)&Xh[scc][sr][sco + 8] = hi1;
      *(bf16x8*)&Xl[scc][sr][sco] = lo0;
      *(bf16x8*)&Xl[scc][sr][sco + 8] = lo1;
    }
    __syncthreads();

    bf16x8 ah[2], al[2];
    #pragma unroll
    for (int c = 0; c < 2; c++) {
      ah[c] = *(const bf16x8*)&Xh[c][w * 16 + low][quad * 8];
      al[c] = *(const bf16x8*)&Xl[c][w * 16 + low][quad * 8];
    }

    floatx4 acc[4];
    #pragma unroll
    for (int nn = 0; nn < 4; nn++) {
      floatx4 a = {};
      #pragma unroll
      for (int c = 0; c < 2; c++) {
        const __hip_bfloat16* wp = Wh + (nn * 16 + low) * 64 + c * 32 + quad * 8;
        bf16x8 wh_ = *(const bf16x8*)wp;
        bf16x8 wl_ = *(const bf16x8*)(wp + 4096);
        a = __builtin_amdgcn_mfma_f32_16x16x32_bf16(ah[c], wh_, a, 0, 0, 0);
        a = __builtin_amdgcn_mfma_f32_16x16x32_bf16(al[c], wh_, a, 0, 0, 0);
        a = __builtin_amdgcn_mfma_f32_16x16x32_bf16(ah[c], wl_, a, 0, 0, 0);
      }
      acc[nn] = a;
    }

    if (m < 2) {
      __hip_bfloat16* dh = (m == 0) ? qhi : khi;
      __hip_bfloat16* dl = (m == 0) ? qlo : klo;
      #pragma unroll
      for (int nn = 0; nn < 4; nn++) {
        #pragma unroll
        for (int i = 0; i < 4; i++) {
          const int s = s0 + w * 16 + quad * 4 + i;
          const int d = nn * 16 + low;
          const size_t adr = ((size_t)bh * S_ + s) * 64 + d;
          const float f = acc[nn][i];
          const __hip_bfloat16 hb = __float2bfloat16(f);
          dh[adr] = hb;
          dl[adr] = __float2bfloat16(f - __bfloat162float(hb));
        }
      }
    } else {
      #pragma unroll
      for (int nn = 0; nn < 4; nn++)
        #pragma unroll
        for (int i = 0; i < 4; i++)
          Vt[nn * 16 + low][w * 16 + quad * 4 + i] = (__bf16)acc[nn][i];
      __syncthreads();
      const int dr = t >> 2;
      const int scl = (t & 3) * 16;
      __hip_bfloat16* dst = vt + ((size_t)bh * 64 + dr) * S_ + s0 + scl;
      bf16x8 o0 = *(const bf16x8*)&Vt[dr][scl];
      bf16x8 o1 = *(const bf16x8*)&Vt[dr][scl + 8];
      *(bf16x8*)dst = o0;
      *(bf16x8*)(dst + 8) = o1;
    }
  }
}

// ---------------------------------------------------------------------------
// MFMA flash attention (unchanged from round 3).
// ---------------------------------------------------------------------------
__global__ __launch_bounds__(256) void attn_mfma(
    const __hip_bfloat16* __restrict__ Qhi, const __hip_bfloat16* __restrict__ Qlo,
    const __hip_bfloat16* __restrict__ Khi, const __hip_bfloat16* __restrict__ Klo,
    const __hip_bfloat16* __restrict__ Vtg, __hip_bfloat16* __restrict__ ctx) {
  __shared__ __bf16 Qh[2][64][32], Ql[2][64][32];
  __shared__ __bf16 Kh[2][64][32], Kl[2][64][32];
  __shared__ __bf16 Vs[2][64][32];
  __shared__ __bf16 Ps[4][2][16][32];
  const int t = threadIdx.x, lane = t & 63, w = t >> 6;
  const int quad = lane >> 4, low = lane & 15;
  const int bh = blockIdx.y;
  const int q0 = blockIdx.x * 64;

  const int sr = t >> 2;
  const int sc = (t & 3) * 16;
  const int scc = sc >> 5, sco = sc & 31;

  {
    const size_t g = ((size_t)bh * S_ + q0 + sr) * 64 + sc;
    bf16x8 h0 = *(const bf16x8*)(Qhi + g);
    bf16x8 h1 = *(const bf16x8*)(Qhi + g + 8);
    bf16x8 l0 = *(const bf16x8*)(Qlo + g);
    bf16x8 l1 = *(const bf16x8*)(Qlo + g + 8);
    *(bf16x8*)&Qh[scc][sr][sco] = h0; *(bf16x8*)&Qh[scc][sr][sco + 8] = h1;
    *(bf16x8*)&Ql[scc][sr][sco] = l0; *(bf16x8*)&Ql[scc][sr][sco + 8] = l1;
  }
  __syncthreads();
  bf16x8 qh[2], ql[2];
  #pragma unroll
  for (int c = 0; c < 2; c++) {
    qh[c] = *(const bf16x8*)&Qh[c][w * 16 + low][quad * 8];
    ql[c] = *(const bf16x8*)&Ql[c][w * 16 + low][quad * 8];
  }

  floatx4 oacc[4] = {};
  float mrow[4], lrow[4];
  #pragma unroll
  for (int i = 0; i < 4; i++) { mrow[i] = -1e30f; lrow[i] = 0.f; }

  for (int kt = 0; kt < S_ / 64; kt++) {
    const size_t gk = ((size_t)bh * S_ + kt * 64 + sr) * 64 + sc;
    const size_t gv = ((size_t)bh * 64 + sr) * S_ + kt * 64 + sc;
    bf16x8 kh0 = *(const bf16x8*)(Khi + gk);
    bf16x8 kh1 = *(const bf16x8*)(Khi + gk + 8);
    bf16x8 kl0 = *(const bf16x8*)(Klo + gk);
    bf16x8 kl1 = *(const bf16x8*)(Klo + gk + 8);
    bf16x8 vv0 = *(const bf16x8*)(Vtg + gv);
    bf16x8 vv1 = *(const bf16x8*)(Vtg + gv + 8);
    __syncthreads();
    *(bf16x8*)&Kh[scc][sr][sco] = kh0; *(bf16x8*)&Kh[scc][sr][sco + 8] = kh1;
    *(bf16x8*)&Kl[scc][sr][sco] = kl0; *(bf16x8*)&Kl[scc][sr][sco + 8] = kl1;
    *(bf16x8*)&Vs[scc][sr][sco] = vv0; *(bf16x8*)&Vs[scc][sr][sco + 8] = vv1;
    __syncthreads();

    floatx4 sa[4];
    #pragma unroll
    for (int nn = 0; nn < 4; nn++) {
      bf16x8 kh[2], kl[2];
      #pragma unroll
      for (int c = 0; c < 2; c++) {
        kh[c] = *(const bf16x8*)&Kh[c][nn * 16 + low][quad * 8];
        kl[c] = *(const bf16x8*)&Kl[c][nn * 16 + low][quad * 8];
      }
      floatx4 s = {};
      s = __builtin_amdgcn_mfma_f32_16x16x32_bf16(qh[0], kh[0], s, 0, 0, 0);
      s = __builtin_amdgcn_mfma_f32_16x16x32_bf16(qh[1], kh[1], s, 0, 0, 0);
      s = __builtin_amdgcn_mfma_f32_16x16x32_bf16(ql[0], kh[0], s, 0, 0, 0);
      s = __builtin_amdgcn_mfma_f32_16x16x32_bf16(ql[1], kh[1], s, 0, 0, 0);
      s = __builtin_amdgcn_mfma_f32_16x16x32_bf16(qh[0], kl[0], s, 0, 0, 0);
      s = __builtin_amdgcn_mfma_f32_16x16x32_bf16(qh[1], kl[1], s, 0, 0, 0);
      sa[nn] = s;
    }

    float pv[4][4];
    #pragma unroll
    for (int i = 0; i < 4; i++) {
      float s0 = sa[0][i] * SCALE, s1 = sa[1][i] * SCALE;
      float s2 = sa[2][i] * SCALE, s3 = sa[3][i] * SCALE;
      float rmax = fmaxf(fmaxf(s0, s1), fmaxf(s2, s3));
      rmax = fmaxf(rmax, __shfl_xor(rmax, 1, 64));
      rmax = fmaxf(rmax, __shfl_xor(rmax, 2, 64));
      rmax = fmaxf(rmax, __shfl_xor(rmax, 4, 64));
      rmax = fmaxf(rmax, __shfl_xor(rmax, 8, 64));
      const float nm = fmaxf(mrow[i], rmax);
      const float al = __expf(mrow[i] - nm);
      mrow[i] = nm;
      const float p0 = __expf(s0 - nm), p1 = __expf(s1 - nm);
      const float p2 = __expf(s2 - nm), p3 = __expf(s3 - nm);
      pv[0][i] = p0; pv[1][i] = p1; pv[2][i] = p2; pv[3][i] = p3;
      float rs = (p0 + p1) + (p2 + p3);
      rs += __shfl_xor(rs, 1, 64);
      rs += __shfl_xor(rs, 2, 64);
      rs += __shfl_xor(rs, 4, 64);
      rs += __shfl_xor(rs, 8, 64);
      lrow[i] = lrow[i] * al + rs;
      oacc[0][i] *= al; oacc[1][i] *= al; oacc[2][i] *= al; oacc[3][i] *= al;
    }

    #pragma unroll
    for (int nn = 0; nn < 4; nn++)
      #pragma unroll
      for (int i = 0; i < 4; i++)
        Ps[w][nn >> 1][quad * 4 + i][(nn & 1) * 16 + low] = (__bf16)pv[nn][i];
    bf16x8 pa0 = *(const bf16x8*)&Ps[w][0][low][quad * 8];
    bf16x8 pa1 = *(const bf16x8*)&Ps[w][1][low][quad * 8];

    #pragma unroll
    for (int dt = 0; dt < 4; dt++) {
      bf16x8 vb0 = *(const bf16x8*)&Vs[0][dt * 16 + low][quad * 8];
      bf16x8 vb1 = *(const bf16x8*)&Vs[1][dt * 16 + low][quad * 8];
      oacc[dt] = __builtin_amdgcn_mfma_f32_16x16x32_bf16(pa0, vb0, oacc[dt], 0, 0, 0);
      oacc[dt] = __builtin_amdgcn_mfma_f32_16x16x32_bf16(pa1, vb1, oacc[dt], 0, 0, 0);
    }
  }

  const int b = bh >> 4, h = bh & 15;
  #pragma unroll
  for (int i = 0; i < 4; i++) {
    const float inv = 1.0f / lrow[i];
    const int row = q0 + w * 16 + quad * 4 + i;
    const size_t base = ((size_t)(b * S_ + row)) * E_ + h * 64 + low;
    #pragma unroll
    for (int dt = 0; dt < 4; dt++)
      ctx[base + dt * 16] = __float2bfloat16(oacc[dt][i] * inv);
  }
}

// ---------------------------------------------------------------------------
// bf16 MFMA GEMM (unchanged, validated)
// ---------------------------------------------------------------------------
template <int RELU, int OUT_BF16>
__global__ __launch_bounds__(256) void gemm_mfma(
    const __hip_bfloat16* __restrict__ A, const __hip_bfloat16* __restrict__ Wt,
    const float* __restrict__ bias, void* __restrict__ Cout,
    int M, int N, int K) {
  __shared__ __bf16 As[128][32];
  __shared__ __bf16 Bs[128][32];
  const int t = threadIdx.x;
  const int lane = t & 63;
  const int w = t >> 6;
  const int wr = w >> 1, wc = w & 1;
  const int m0 = blockIdx.y * 128, n0 = blockIdx.x * 128;

  floatx4 acc[4][4] = {};
  const int srow = t >> 2;
  const int schunk = (t & 3) * 8;

  const __hip_bfloat16* gA0 = A + (size_t)(m0 + srow) * K + schunk;
  const __hip_bfloat16* gA1 = A + (size_t)(m0 + srow + 64) * K + schunk;
  const __hip_bfloat16* gB0 = Wt + (size_t)(n0 + srow) * K + schunk;
  const __hip_bfloat16* gB1 = Wt + (size_t)(n0 + srow + 64) * K + schunk;

  for (int k0 = 0; k0 < K; k0 += 32) {
    bf16x8 a0 = *(const bf16x8*)(gA0 + k0);
    bf16x8 a1 = *(const bf16x8*)(gA1 + k0);
    bf16x8 b0 = *(const bf16x8*)(gB0 + k0);
    bf16x8 b1 = *(const bf16x8*)(gB1 + k0);
    __syncthreads();
    *(bf16x8*)&As[srow][schunk] = a0;
    *(bf16x8*)&As[srow + 64][schunk] = a1;
    *(bf16x8*)&Bs[srow][schunk] = b0;
    *(bf16x8*)&Bs[srow + 64][schunk] = b1;
    __syncthreads();

    bf16x8 af[4], bf[4];
    #pragma unroll
    for (int i = 0; i < 4; i++) {
      af[i] = *(const bf16x8*)&As[wr * 64 + i * 16 + (lane & 15)][(lane >> 4) * 8];
      bf[i] = *(const bf16x8*)&Bs[wc * 64 + i * 16 + (lane & 15)][(lane >> 4) * 8];
    }
    #pragma unroll
    for (int mi = 0; mi < 4; mi++)
      #pragma unroll
      for (int ni = 0; ni < 4; ni++)
        acc[mi][ni] = __builtin_amdgcn_mfma_f32_16x16x32_bf16(
            af[mi], bf[ni], acc[mi][ni], 0, 0, 0);
  }

  const int cil = lane & 15;
  const int quad = lane >> 4;
  #pragma unroll
  for (int ni = 0; ni < 4; ni++) {
    const int col = n0 + wc * 64 + ni * 16 + cil;
    const float bb = bias[col];
    #pragma unroll
    for (int mi = 0; mi < 4; mi++) {
      const int row = m0 + wr * 64 + mi * 16 + quad * 4;
      #pragma unroll
      for (int i = 0; i < 4; i++) {
        float vv = acc[mi][ni][i] + bb;
        if (RELU) vv = fmaxf(vv, 0.f);
        if (OUT_BF16)
          ((__hip_bfloat16*)Cout)[(size_t)(row + i) * N + col] = __float2bfloat16(vv);
        else
          ((float*)Cout)[(size_t)(row + i) * N + col] = vv;
      }
    }
  }
}

// ---------------------------------------------------------------------------
// out = LayerNorm(a + r)*g + b ; optional secondary bf16 output
// ---------------------------------------------------------------------------
template <int EMIT_BF16>
__global__ __launch_bounds__(256) void add_ln(
    const float* __restrict__ a, const float* __restrict__ r,
    const float* __restrict__ g, const float* __restrict__ bt,
    float* __restrict__ out, __hip_bfloat16* __restrict__ outb) {
  __shared__ float red[16];
  const int tok = blockIdx.x, t = threadIdx.x;
  float4 av = ((const float4*)(a + (size_t)tok * E_))[t];
  float4 rv = ((const float4*)(r + (size_t)tok * E_))[t];
  float4 x;
  x.x = av.x + rv.x; x.y = av.y + rv.y; x.z = av.z + rv.z; x.w = av.w + rv.w;
  float sum = x.x + x.y + x.z + x.w;
  float ssq = x.x * x.x + x.y * x.y + x.z * x.z + x.w * x.w;
  #pragma unroll
  for (int off = 32; off >= 1; off >>= 1) {
    sum += __shfl_down(sum, off, 64);
    ssq += __shfl_down(ssq, off, 64);
  }
  const int wave = t >> 6;
  if ((t & 63) == 0) { red[wave] = sum; red[4 + wave] = ssq; }
  __syncthreads();
  if (t == 0) {
    float s = red[0] + red[1] + red[2] + red[3];
    float qq = red[4] + red[5] + red[6] + red[7];
    float mu = s * (1.0f / E_);
    red[8] = mu;
    red[9] = qq * (1.0f / E_) - mu * mu;
  }
  __syncthreads();
  const float mu = red[8];
  const float inv = rsqrtf(red[9] + 1e-5f);
  float4 gv = ((const float4*)g)[t];
  float4 bv = ((const float4*)bt)[t];
  float4 o;
  o.x = (x.x - mu) * inv * gv.x + bv.x;
  o.y = (x.y - mu) * inv * gv.y + bv.y;
  o.z = (x.z - mu) * inv * gv.z + bv.z;
  o.w = (x.w - mu) * inv * gv.w + bv.w;
  ((float4*)(out + (size_t)tok * E_))[t] = o;
  if (EMIT_BF16) {
    b4s ob;
    ob.x = __float2bfloat16(o.x); ob.y = __float2bfloat16(o.y);
    ob.z = __float2bfloat16(o.z); ob.w = __float2bfloat16(o.w);
    *(b4s*)(outb + (size_t)tok * E_ + t * 4) = ob;
  }
}

// ---------------------------------------------------------------------------
extern "C" void kernel_launch(void* const* d_in, const int* in_sizes, int n_in,
                              void* d_out, int out_size, void* d_ws, size_t ws_size,
                              hipStream_t stream) {
  const float* queries = (const float*)d_in[0];
  const float* keys    = (const float*)d_in[1];
  const float* values  = (const float*)d_in[2];
  const float* Wq  = (const float*)d_in[4];
  const float* Wk  = (const float*)d_in[5];
  const float* Wv  = (const float*)d_in[6];
  const float* Wfc = (const float*)d_in[7];
  const float* bfc = (const float*)d_in[8];
  const float* W1  = (const float*)d_in[9];
  const float* b1  = (const float*)d_in[10];
  const float* W2  = (const float*)d_in[11];
  const float* b2  = (const float*)d_in[12];
  const float* ln1_g = (const float*)d_in[13];
  const float* ln1_b = (const float*)d_in[14];
  const float* ln2_g = (const float*)d_in[15];
  const float* ln2_b = (const float*)d_in[16];

  const size_t M1 = 1048576;
  float* ws = (float*)d_ws;
  float* ATT = ws;             // 4M fl
  float* Hf  = ws + 4 * M1;    // 4M fl
  float* X   = ws + 8 * M1;    // 4M fl
  __hip_bfloat16* bb = (__hip_bfloat16*)(ws + 12 * M1);
  __hip_bfloat16* CTXb = bb;                  //  4M
  __hip_bfloat16* Hb   = bb + 4 * M1;         //  4M
  __hip_bfloat16* Wfcb = bb + 8 * M1;         //  1M
  __hip_bfloat16* W1b  = bb + 9 * M1;         //  4M
  __hip_bfloat16* W2b  = bb + 13 * M1;        //  4M
  // attention temps (17M..37M) alias FF1b (17M..33M): FF1b written after attn
  __hip_bfloat16* Qhi  = bb + 17 * M1;        //  4M
  __hip_bfloat16* Qlo  = bb + 21 * M1;        //  4M
  __hip_bfloat16* Khi  = bb + 25 * M1;        //  4M
  __hip_bfloat16* Klo  = bb + 29 * M1;        //  4M
  __hip_bfloat16* Vtb  = bb + 33 * M1;        //  4M
  __hip_bfloat16* FF1b = bb + 17 * M1;        // 16M (after attention)
  __hip_bfloat16* Whlb = bb + 37 * M1;        // 24K (3 x hi/lo x 4096)
  float* out = (float*)d_out;

  cast_f2b<<<(E_ * E_ / 4 + 255) / 256, 256, 0, stream>>>(Wfc, Wfcb, E_ * E_ / 4);
  cast_f2b<<<(4 * E_ * E_ / 4 + 255) / 256, 256, 0, stream>>>(W1, W1b, 4 * E_ * E_ / 4);
  cast_f2b<<<(4 * E_ * E_ / 4 + 255) / 256, 256, 0, stream>>>(W2, W2b, 4 * E_ * E_ / 4);
  cast_whl<<<12, 256, 0, stream>>>(Wq, Wk, Wv, Whlb);

  qkv_fused<<<dim3(S_ / 64, B_ * H_), 256, 0, stream>>>(
      queries, keys, values, Whlb, Qhi, Qlo, Khi, Klo, Vtb);
  attn_mfma<<<dim3(S_ / 64, B_ * H_), 256, 0, stream>>>(Qhi, Qlo, Khi, Klo, Vtb, CTXb);
  gemm_mfma<0, 0><<<dim3(E_ / 128, TOK / 128), 256, 0, stream>>>(
      CTXb, Wfcb, bfc, ATT, TOK, E_, E_);
  add_ln<1><<<TOK, 256, 0, stream>>>(ATT, queries, ln1_g, ln1_b, Hf, Hb);
  gemm_mfma<1, 1><<<dim3(4 * E_ / 128, TOK / 128), 256, 0, stream>>>(
      Hb, W1b, b1, FF1b, TOK, 4 * E_, E_);
  gemm_mfma<0, 0><<<dim3(E_ / 128, TOK / 128), 256, 0, stream>>>(
      FF1b, W2b, b2, X, TOK, E_, 4 * E_);
  add_ln<0><<<TOK, 256, 0, stream>>>(X, Hf, ln2_g, ln2_b, out, nullptr);
}